// Round 11
// baseline (360.872 us; speedup 1.0000x reference)
//
#include <hip/hip_runtime.h>
#include <math.h>

#define BATCH 4
#define TLEN 512
#define SLEN 512
#define DM 256
#define NH 4
#define DH 64
#define BT (BATCH * TLEN)   // 2048
#define NBLK 1024           // 4 blocks/CU x 256 CU: co-resident by construction

__device__ __forceinline__ float rcp_fast(float x) { return __builtin_amdgcn_rcpf(x); }

// grid-wide barrier: all NBLK blocks co-resident (4/CU: LDS 32KB, VGPR<=128 via launch_bounds).
// release fence (wbl2) before arrival, acquire fence (inv) after spin -> cross-XCD safe.
__device__ __forceinline__ void grid_barrier(unsigned* ctr) {
  __syncthreads();
  if (threadIdx.x == 0) {
    __threadfence();                                    // release: L2 writeback
    __hip_atomic_fetch_add(ctr, 1u, __ATOMIC_RELAXED, __HIP_MEMORY_SCOPE_AGENT);
    while (__hip_atomic_load(ctr, __ATOMIC_RELAXED, __HIP_MEMORY_SCOPE_AGENT) < NBLK)
      __builtin_amdgcn_s_sleep(8);
    __threadfence();                                    // acquire: L1/L2 invalidate
  }
  __syncthreads();
}

// ---- staged-panel GEMM: block covers (RPT*4 rows x 64 outs). W panel (64o x 256k) staged
//      per 128-k half into LDS [64][128] with f ^= (o&7) float4-XOR swizzle:
//      - stage writes: 32 lanes same o, f=0..31 -> all 8 bank-groups, conflict-free
//      - reads: lane=o, uniform physical k-group g, slot g^(lane&7): 8 distinct bank-groups
//        across 8-lane sets -> conflict-free at the b128 wave floor
//      X rows wave-uniform -> scalar loads (physical k order preserved). ----
template <int RPT>
__device__ __forceinline__ void panel_gemm(const float* __restrict__ X,
                                           const float* __restrict__ W,
                                           float* wl, int o0, int wrow0,
                                           int tid, int lane, float* acc) {
#pragma unroll
  for (int r = 0; r < RPT; ++r) acc[r] = 0.f;
#pragma unroll 1
  for (int half = 0; half < 2; ++half) {
    __syncthreads();                                    // previous half / prior phase done
    const float4* wsrc = (const float4*)(W + (size_t)o0 * DM + half * 128);
#pragma unroll
    for (int i = 0; i < 8; ++i) {
      int c = i * 256 + tid;
      int o = c >> 5, f = c & 31;
      *(float4*)&wl[o * 128 + 4 * (f ^ (o & 7))] = wsrc[(size_t)o * 64 + f];
    }
    __syncthreads();
    const float* xh = X + (size_t)wrow0 * DM + half * 128;   // wave-uniform
#pragma unroll 4
    for (int g = 0; g < 32; ++g) {
      float4 w = *(const float4*)&wl[lane * 128 + 4 * (g ^ (lane & 7))];
#pragma unroll
      for (int r = 0; r < RPT; ++r) {
        const float* xr = xh + r * DM + g * 4;
        acc[r] = fmaf(xr[0], w.x, acc[r]);
        acc[r] = fmaf(xr[1], w.y, acc[r]);
        acc[r] = fmaf(xr[2], w.z, acc[r]);
        acc[r] = fmaf(xr[3], w.w, acc[r]);
      }
    }
  }
}

// ---- attn tile (R9-proven body): vtile = (bh, 4 t-rows); wave owns s-quarter ----
#define LOADE(EV, dc_) do { EV##0 = ekf[(size_t)(dc_) * SLEN]; \
                            EV##1 = ekf[(size_t)(dc_) * SLEN + 64]; } while (0)
#define SC4(E, qv, av, aref) do {                                           \
    float A0 = fmaf(qv.x, E.x, 1.f), A1 = fmaf(qv.y, E.y, 1.f);             \
    float A2 = fmaf(qv.z, E.z, 1.f), A3 = fmaf(qv.w, E.w, 1.f);             \
    float n01 = fmaf(av.x, A1, av.y * A0);                                  \
    float n23 = fmaf(av.z, A3, av.w * A2);                                  \
    float P01 = A0 * A1, P23 = A2 * A3;                                     \
    float Nm = fmaf(n01, P23, n23 * P01);                                   \
    aref = fmaf(Nm, rcp_fast(P01 * P23), aref);                             \
  } while (0)
#define DCBODY(CUR, NXT, dc_) do {                                          \
    float4 av = *(const float4*)(vap + (dc_) * 4);                          \
    float4 q0 = *(const float4*)(eqb + 0 * DH + (dc_) * 4);                 \
    float4 q1 = *(const float4*)(eqb + 1 * DH + (dc_) * 4);                 \
    float4 q2 = *(const float4*)(eqb + 2 * DH + (dc_) * 4);                 \
    float4 q3 = *(const float4*)(eqb + 3 * DH + (dc_) * 4);                 \
    vsum += (av.x + av.y) + (av.z + av.w);                                  \
    if ((dc_) < 15) LOADE(NXT, (dc_) + 1);                                  \
    __builtin_amdgcn_sched_barrier(0);                                      \
    SC4(CUR##0, q0, av, acc[0][0]); SC4(CUR##1, q0, av, acc[0][1]);         \
    SC4(CUR##0, q1, av, acc[1][0]); SC4(CUR##1, q1, av, acc[1][1]);         \
    SC4(CUR##0, q2, av, acc[2][0]); SC4(CUR##1, q2, av, acc[2][1]);         \
    SC4(CUR##0, q3, av, acc[3][0]); SC4(CUR##1, q3, av, acc[3][1]);         \
  } while (0)

__device__ __forceinline__ void attn_tile(int bxv,
    const float* __restrict__ EQ, const float* __restrict__ EKT,
    const float* __restrict__ Vw, const float* __restrict__ va_g,
    float* __restrict__ attn_out, float* __restrict__ attended,
    float* smem, int tid, int lane, int wid) {
  float* pwf   = smem;           // [4][512] probs
  float* fpf   = smem + 2048;    // [4 waves][4 t][64] PV partials
  float* sredf = smem + 3072;    // [4 t][4 waves] softmax sums
  int bx = (bxv & 7) * 256 + (bxv >> 3);      // bijective XCD swizzle over 2048
  int bh = bx >> 7;
  int tile = (bx & 127) * 4;
  int h = bh & 3, b = bh >> 2;
  int sq0 = wid * 128;

  const float4* ekf = (const float4*)EKT + (size_t)bh * (16 * SLEN) + sq0 + lane;
  const float* eqb = EQ + ((size_t)bh * TLEN + tile) * DH;
  const float* vap = va_g + h * DH;

  float acc[4][2];
#pragma unroll
  for (int t = 0; t < 4; ++t) { acc[t][0] = 0.f; acc[t][1] = 0.f; }
  float vsum = 0.f;
  float4 eA0, eA1, eB0, eB1;

  LOADE(eA, 0);
#pragma unroll 1
  for (int dc2 = 0; dc2 < 8; ++dc2) {
    DCBODY(eA, eB, 2 * dc2);
    DCBODY(eB, eA, 2 * dc2 + 1);
  }

  // softmax, no max-subtraction (|score| <= 0.125*sum|va| ~ 7, exp bounded)
  size_t bht = (size_t)bh * TLEN + tile;
  float e0[4], e1[4];
#pragma unroll
  for (int t = 0; t < 4; ++t) {
    float x0 = __expf(fmaf(acc[t][0], -0.25f, vsum * 0.125f));
    float x1 = __expf(fmaf(acc[t][1], -0.25f, vsum * 0.125f));
    e0[t] = x0; e1[t] = x1;
    float es = x0 + x1;
#pragma unroll
    for (int off = 32; off; off >>= 1) es += __shfl_xor(es, off);
    if (lane == 0) sredf[t * 4 + wid] = es;
  }
  __syncthreads();
#pragma unroll
  for (int t = 0; t < 4; ++t) {
    float es = (sredf[t * 4 + 0] + sredf[t * 4 + 1]) + (sredf[t * 4 + 2] + sredf[t * 4 + 3]);
    float inv = rcp_fast(es);
    float p0 = e0[t] * inv, p1 = e1[t] * inv;
    pwf[t * SLEN + sq0 + lane] = p0;          // own-wave region
    pwf[t * SLEN + sq0 + 64 + lane] = p1;
    float* arow = attn_out + (bht + t) * SLEN + sq0;
    arow[lane] = p0;
    arow[64 + lane] = p1;
  }

  // PV over own s-quarter
  const float2* vb = (const float2*)Vw + (size_t)bh * (256 * 64) + (size_t)(wid * 64) * 64 + lane;
  float f[4];
#pragma unroll
  for (int t = 0; t < 4; ++t) f[t] = 0.f;
#pragma unroll 2
  for (int i = 0; i < 32; ++i) {
    float2 v01 = vb[(size_t)i * 128];
    float2 v23 = vb[(size_t)i * 128 + 64];
    int sb = sq0 + i * 4;
#pragma unroll
    for (int t = 0; t < 4; ++t) {
      float4 pq = *(const float4*)&pwf[t * SLEN + sb];
      f[t] = fmaf(pq.x, v01.x, f[t]);
      f[t] = fmaf(pq.y, v01.y, f[t]);
      f[t] = fmaf(pq.z, v23.x, f[t]);
      f[t] = fmaf(pq.w, v23.y, f[t]);
    }
  }
#pragma unroll
  for (int t = 0; t < 4; ++t) fpf[(wid * 4 + t) * 64 + lane] = f[t];
  __syncthreads();
  {
    int t = wid;
    float s = (fpf[(0 * 4 + t) * 64 + lane] + fpf[(1 * 4 + t) * 64 + lane]) +
              (fpf[(2 * 4 + t) * 64 + lane] + fpf[(3 * 4 + t) * 64 + lane]);
    attended[((size_t)(b * TLEN) + tile + t) * DM + h * DH + lane] = s;
  }
}

// ---- the single persistent kernel: P1 proj -> bar -> P2 attn x2 -> bar -> P3 outproj ----
__global__ __launch_bounds__(256, 4) void fused_kernel(
    const float* __restrict__ q, const float* __restrict__ k, const float* __restrict__ v,
    const float* __restrict__ wq, const float* __restrict__ wk, const float* __restrict__ wv,
    const float* __restrict__ va, const float* __restrict__ wo,
    float* __restrict__ EQ, float* __restrict__ EKT, float* __restrict__ Vw,
    float* __restrict__ att, float* __restrict__ out, float* __restrict__ attn_probs,
    unsigned* bar0, unsigned* bar1) {
  __shared__ float smem[8192];                 // 32 KB: P1/P3 W panel; P2 attn scratch
  int tid = threadIdx.x;
  int lane = tid & 63;
  int wid = __builtin_amdgcn_readfirstlane(tid >> 6);
  int pb = blockIdx.x;

  // ---- P1: Q/K/V projections (768 vblocks: 3 mats x 64 rowtiles(32) x 4 o-slices) ----
  if (pb < 768) {
    int m = pb >> 8, sub = pb & 255;
    int wrow0 = (sub >> 2) * 32 + wid * 8;
    int o0 = (sub & 3) * 64;
    const float* X = (m == 0) ? q : (m == 1) ? k : v;
    const float* W = (m == 0) ? wq : (m == 1) ? wk : wv;
    float acc[8];
    panel_gemm<8>(X, W, smem, o0, wrow0, tid, lane, acc);
    int o = o0 + lane, h = o >> 6, d = o & 63;
#pragma unroll
    for (int r = 0; r < 8; ++r) {
      int row = wrow0 + r;
      int b = row >> 9, t = row & 511;
      int bh = b * NH + h;
      float val = acc[r];
      if (m < 2) {
        // clamp +-5.5 (6.9 sigma; P(hit)~3e-6): quad product <= e^88 < fp32 max
        val = __expf(2.f * fminf(fmaxf(val, -5.5f), 5.5f));
      }
      if (m == 0) {
        EQ[((size_t)bh * TLEN + t) * DH + d] = val;
      } else if (m == 1) {
        EKT[(((size_t)bh * 16 + (d >> 2)) * SLEN + t) * 4 + (d & 3)] = val;
      } else {
        Vw[(size_t)bh * SLEN * DH + (size_t)(t >> 1) * 128 + d * 2 + (t & 1)] = val;
      }
    }
  }
  grid_barrier(bar0);      // bar0 overlays att[last]: clobbered only by P2 (post-release: dead)

  // ---- P2: attention, 2048 vtiles on 1024 blocks ----
  attn_tile(pb,        EQ, EKT, Vw, va, attn_probs, att, smem, tid, lane, wid);
  attn_tile(pb + 1024, EQ, EKT, Vw, va, attn_probs, att, smem, tid, lane, wid);

  grid_barrier(bar1);      // bar1 overlays out[last]: clobbered only by P3 (dead by then)

  // ---- P3: out = attended @ wo^T (512 vblocks: 128 rowtiles(16) x 4 o-slices) ----
  if (pb < 512) {
    int wrow0 = (pb >> 2) * 16 + wid * 4;
    int o0 = (pb & 3) * 64;
    float acc[4];
    panel_gemm<4>(att, wo, smem, o0, wrow0, tid, lane, acc);
    int o = o0 + lane;
#pragma unroll
    for (int r = 0; r < 4; ++r)
      out[(size_t)(wrow0 + r) * DM + o] = acc[r];
  }
}

extern "C" void kernel_launch(void* const* d_in, const int* in_sizes, int n_in,
                              void* d_out, int out_size, void* d_ws, size_t ws_size,
                              hipStream_t stream) {
  const float* query = (const float*)d_in[0];
  const float* key   = (const float*)d_in[1];
  const float* value = (const float*)d_in[2];
  const float* wq    = (const float*)d_in[3];
  const float* wk    = (const float*)d_in[4];
  const float* wv    = (const float*)d_in[5];
  const float* va    = (const float*)d_in[6];
  const float* wo    = (const float*)d_in[7];

  float* out  = (float*)d_out;                 // (B,T,DM) = 524288 floats
  float* attn = out + (size_t)BT * DM;         // (B,H,T,S) = 4194304 floats

  const size_t SEG = (size_t)BT * DM;          // 524288 floats = 2MB
  float* EQ  = (float*)d_ws;                   // [bh][t][d]
  float* EKT = EQ + SEG;                       // [bh][dc16][s][j4]
  float* Vw  = EKT + SEG;                      // [bh][s/2][d][2]
  float* att = Vw + SEG;                       // attended [b][t][h*64+d]

  // barrier counters overlaid on the LAST element of the buffer each *following* phase writes:
  // by the time those writes clobber them, every block has passed the barrier (counter dead).
  unsigned* bar0 = (unsigned*)(att + SEG - 1);          // attended[last], written in P2
  unsigned* bar1 = (unsigned*)(out + SEG - 1);          // out[last], written in P3
  hipMemsetAsync(bar0, 0, 4, stream);
  hipMemsetAsync(bar1, 0, 4, stream);

  fused_kernel<<<dim3(NBLK), 256, 0, stream>>>(
      query, key, value, wq, wk, wv, va, wo,
      EQ, EKT, Vw, att, out, attn, bar0, bar1);
}

// Round 12
// 93.048 us; speedup vs baseline: 3.8783x; 3.8783x over previous
//
#include <hip/hip_runtime.h>
#include <math.h>

#define BATCH 4
#define TLEN 512
#define SLEN 512
#define DM 256
#define NH 4
#define DH 64
#define BT (BATCH * TLEN)   // 2048
#define KP 65               // padded o-stride for transposed W panel in LDS

__device__ __forceinline__ float rcp_fast(float x) { return __builtin_amdgcn_rcpf(x); }

// ---- self-staged GEMM, transposed panel: block = (RPT*4 rows x 64 outs).
//      W panel (64o x 256k, original row-major) staged per 128-k half into
//      LDS wl[k][o] with o-stride 65:
//        reads  wl[k*KP + lane]: banks = (k*KP+lane)%32 -> 32 distinct, 2-way FREE
//        stage  writes 4-way (32 wave-writes/half, negligible)
//      X rows wave-uniform -> batched s_load_dwordx4 per k4. ----
template <int RPT>
__device__ __forceinline__ void panel_gemm(const float* __restrict__ X,
                                           const float* __restrict__ W,
                                           float* __restrict__ wl,
                                           int o0, int wrow0,
                                           int tid, int lane, float* acc) {
#pragma unroll
  for (int r = 0; r < RPT; ++r) acc[r] = 0.f;
#pragma unroll 1
  for (int half = 0; half < 2; ++half) {
    __syncthreads();                                   // previous half consumed
    const float4* wsrc = (const float4*)(W + (size_t)o0 * DM + half * 128);
#pragma unroll
    for (int i = 0; i < 8; ++i) {                      // coalesced global float4
      int c = i * 256 + tid;
      int o = c >> 5, k4 = c & 31;
      float4 wv = wsrc[(size_t)o * 64 + k4];
      wl[(4 * k4 + 0) * KP + o] = wv.x;                // transpose into [k][o]
      wl[(4 * k4 + 1) * KP + o] = wv.y;
      wl[(4 * k4 + 2) * KP + o] = wv.z;
      wl[(4 * k4 + 3) * KP + o] = wv.w;
    }
    __syncthreads();
    const float* xh = X + (size_t)wrow0 * DM + half * 128;   // wave-uniform
#pragma unroll 4
    for (int k4 = 0; k4 < 32; ++k4) {
      float4 xr[RPT];
#pragma unroll
      for (int r = 0; r < RPT; ++r)
        xr[r] = *(const float4*)(xh + r * DM + 4 * k4);      // s_load_dwordx4
      float w0 = wl[(4 * k4 + 0) * KP + lane];         // conflict-free b32
      float w1 = wl[(4 * k4 + 1) * KP + lane];
      float w2 = wl[(4 * k4 + 2) * KP + lane];
      float w3 = wl[(4 * k4 + 3) * KP + lane];
#pragma unroll
      for (int r = 0; r < RPT; ++r) {
        acc[r] = fmaf(xr[r].x, w0, acc[r]);
        acc[r] = fmaf(xr[r].y, w1, acc[r]);
        acc[r] = fmaf(xr[r].z, w2, acc[r]);
        acc[r] = fmaf(xr[r].w, w3, acc[r]);
      }
    }
  }
}

// ---- kernel A: Q/K/V projections, W read directly (no transpose pre-pass).
//      EQ=[bh][t][d]; EKT=[bh][dc16][s][j4]; Vw=[bh][s/2][d][2] ----
__global__ __launch_bounds__(256) void proj_kernel(
    const float* __restrict__ q, const float* __restrict__ k, const float* __restrict__ v,
    const float* __restrict__ wq, const float* __restrict__ wk, const float* __restrict__ wv,
    float* __restrict__ EQ, float* __restrict__ EKT, float* __restrict__ Vw) {
  __shared__ float wl[128 * KP];                       // 33.3 KB
  int tid = threadIdx.x;
  int lane = tid & 63;
  int wid = __builtin_amdgcn_readfirstlane(tid >> 6);
  int which = blockIdx.y;
  const float* X = (which == 0) ? q : (which == 1) ? k : v;
  const float* W = (which == 0) ? wq : (which == 1) ? wk : wv;
  int wrow0 = (blockIdx.x >> 2) * 32 + wid * 8;        // 64 row-tiles of 32
  int o0 = (blockIdx.x & 3) * 64;                      // 4 out-slices of 64
  float acc[8];
  panel_gemm<8>(X, W, wl, o0, wrow0, tid, lane, acc);
  int o = o0 + lane, h = o >> 6, d = o & 63;
#pragma unroll
  for (int r = 0; r < 8; ++r) {
    int row = wrow0 + r;
    int b = row >> 9, t = row & 511;
    int bh = b * NH + h;
    float val = acc[r];
    if (which < 2) {
      // clamp +-5.5 (6.9 sigma; P(hit)~3e-6): quad product A0..A3 <= e^88 < fp32 max
      val = __expf(2.f * fminf(fmaxf(val, -5.5f), 5.5f));
    }
    if (which == 0) {
      EQ[((size_t)bh * TLEN + t) * DH + d] = val;
    } else if (which == 1) {
      EKT[(((size_t)bh * 16 + (d >> 2)) * SLEN + t) * 4 + (d & 3)] = val;
    } else {
      Vw[(size_t)bh * SLEN * DH + (size_t)(t >> 1) * 128 + d * 2 + (t & 1)] = val;
    }
  }
}

// ---- kernel B (byte-identical to R9): block = (bh, 4 t-rows); wave owns s-quarter.
//      grid 2048 -> 8 blocks/CU. Quad-combined rcp: 1 v_rcp per 4 d. ----
__global__ __launch_bounds__(256, 8) void attn_kernel(
    const float* __restrict__ EQ, const float* __restrict__ EKT,
    const float* __restrict__ Vw, const float* __restrict__ va_g,
    float* __restrict__ attn_out, float* __restrict__ attended) {
  __shared__ float pw[4][SLEN];      // probs, t-major
  __shared__ float fp[4][4][64];     // per-wave PV partials
  __shared__ float sred[4][4];       // cross-wave softmax sums
  int tid = threadIdx.x;
  int lane = tid & 63;
  int wid = __builtin_amdgcn_readfirstlane(tid >> 6);
  int bx = (int)((blockIdx.x & 7) * 256 + (blockIdx.x >> 3));  // bijective XCD swizzle (2048=8*256)
  int bh = bx >> 7;
  int tile = (bx & 127) * 4;
  int h = bh & 3, b = bh >> 2;
  int sq0 = wid * 128;               // this wave's s-quarter base

  const float4* ekf = (const float4*)EKT + (size_t)bh * (16 * SLEN) + sq0 + lane;
  const float* eqb = EQ + ((size_t)bh * TLEN + tile) * DH;   // uniform -> s_load
  const float* vap = va_g + h * DH;

  float acc[4][2];
#pragma unroll
  for (int t = 0; t < 4; ++t) { acc[t][0] = 0.f; acc[t][1] = 0.f; }
  float vsum = 0.f;

  float4 eA0, eA1, eB0, eB1;

#define LOADE(EV, dc_) do { EV##0 = ekf[(size_t)(dc_) * SLEN]; \
                            EV##1 = ekf[(size_t)(dc_) * SLEN + 64]; } while (0)

  // sum_{j=0..3} va_j/A_j = (n01*P23 + n23*P01) / (P01*P23): 14 VALU + 1 rcp
#define SC4(E, qv, av, aref) do {                                           \
    float A0 = fmaf(qv.x, E.x, 1.f), A1 = fmaf(qv.y, E.y, 1.f);             \
    float A2 = fmaf(qv.z, E.z, 1.f), A3 = fmaf(qv.w, E.w, 1.f);             \
    float n01 = fmaf(av.x, A1, av.y * A0);                                  \
    float n23 = fmaf(av.z, A3, av.w * A2);                                  \
    float P01 = A0 * A1, P23 = A2 * A3;                                     \
    float Nm = fmaf(n01, P23, n23 * P01);                                   \
    aref = fmaf(Nm, rcp_fast(P01 * P23), aref);                             \
  } while (0)

#define DCBODY(CUR, NXT, dc_) do {                                          \
    float4 av = *(const float4*)(vap + (dc_) * 4);                          \
    float4 q0 = *(const float4*)(eqb + 0 * DH + (dc_) * 4);                 \
    float4 q1 = *(const float4*)(eqb + 1 * DH + (dc_) * 4);                 \
    float4 q2 = *(const float4*)(eqb + 2 * DH + (dc_) * 4);                 \
    float4 q3 = *(const float4*)(eqb + 3 * DH + (dc_) * 4);                 \
    vsum += (av.x + av.y) + (av.z + av.w);                                  \
    if ((dc_) < 15) LOADE(NXT, (dc_) + 1);                                  \
    __builtin_amdgcn_sched_barrier(0);                                      \
    SC4(CUR##0, q0, av, acc[0][0]); SC4(CUR##1, q0, av, acc[0][1]);         \
    SC4(CUR##0, q1, av, acc[1][0]); SC4(CUR##1, q1, av, acc[1][1]);         \
    SC4(CUR##0, q2, av, acc[2][0]); SC4(CUR##1, q2, av, acc[2][1]);         \
    SC4(CUR##0, q3, av, acc[3][0]); SC4(CUR##1, q3, av, acc[3][1]);         \
  } while (0)

  LOADE(eA, 0);
#pragma unroll 1
  for (int dc2 = 0; dc2 < 8; ++dc2) {
    DCBODY(eA, eB, 2 * dc2);
    DCBODY(eB, eA, 2 * dc2 + 1);
  }

  // ---- softmax, no max-subtraction (|score| <= 0.125*sum|va| ~ 7, exp bounded) ----
  size_t bht = (size_t)bh * TLEN + tile;
  float e0[4], e1[4];
#pragma unroll
  for (int t = 0; t < 4; ++t) {
    float x0 = __expf(fmaf(acc[t][0], -0.25f, vsum * 0.125f));
    float x1 = __expf(fmaf(acc[t][1], -0.25f, vsum * 0.125f));
    e0[t] = x0; e1[t] = x1;
    float es = x0 + x1;
#pragma unroll
    for (int off = 32; off; off >>= 1) es += __shfl_xor(es, off);
    if (lane == 0) sred[t][wid] = es;
  }
  __syncthreads();
#pragma unroll
  for (int t = 0; t < 4; ++t) {
    float es = (sred[t][0] + sred[t][1]) + (sred[t][2] + sred[t][3]);
    float inv = rcp_fast(es);
    float p0 = e0[t] * inv, p1 = e1[t] * inv;
    pw[t][sq0 + lane] = p0;                 // own-wave region: no barrier needed
    pw[t][sq0 + 64 + lane] = p1;
    float* arow = attn_out + (bht + t) * SLEN + sq0;
    arow[lane] = p0;                        // coalesced 256B stores
    arow[64 + lane] = p1;
  }

  // ---- PV over own s-quarter: lane = d; probs via LDS broadcast (own writes) ----
  const float2* vb = (const float2*)Vw + (size_t)bh * (256 * 64) + (size_t)(wid * 64) * 64 + lane;
  float f[4];
#pragma unroll
  for (int t = 0; t < 4; ++t) f[t] = 0.f;
#pragma unroll 2
  for (int i = 0; i < 32; ++i) {            // s-quads within quarter
    float2 v01 = vb[(size_t)i * 128];       // coalesced b64: s-pair, d=lane
    float2 v23 = vb[(size_t)i * 128 + 64];
    int sb = sq0 + i * 4;
#pragma unroll
    for (int t = 0; t < 4; ++t) {
      float4 pq = *(const float4*)&pw[t][sb];   // uniform addr -> LDS broadcast
      f[t] = fmaf(pq.x, v01.x, f[t]);
      f[t] = fmaf(pq.y, v01.y, f[t]);
      f[t] = fmaf(pq.z, v23.x, f[t]);
      f[t] = fmaf(pq.w, v23.y, f[t]);
    }
  }
#pragma unroll
  for (int t = 0; t < 4; ++t) fp[wid][t][lane] = f[t];
  __syncthreads();
  {
    int t = wid;                            // wave reduces 1 t-row
    float s = (fp[0][t][lane] + fp[1][t][lane]) + (fp[2][t][lane] + fp[3][t][lane]);
    attended[((size_t)(b * TLEN) + tile + t) * DM + h * DH + lane] = s;
  }
}

// ---- kernel C: out = attended @ w_o.T, wo staged-transposed in LDS ----
__global__ __launch_bounds__(256) void outproj_kernel(
    const float* __restrict__ att, const float* __restrict__ wo,
    float* __restrict__ out) {
  __shared__ float wl[128 * KP];
  int tid = threadIdx.x;
  int lane = tid & 63;
  int wid = __builtin_amdgcn_readfirstlane(tid >> 6);
  int wrow0 = (blockIdx.x >> 2) * 16 + wid * 4;        // 128 row-tiles of 16
  int o0 = (blockIdx.x & 3) * 64;
  float acc[4];
  panel_gemm<4>(att, wo, wl, o0, wrow0, tid, lane, acc);
  int o = o0 + lane;
#pragma unroll
  for (int r = 0; r < 4; ++r)
    out[(size_t)(wrow0 + r) * DM + o] = acc[r];        // coalesced b32
}

extern "C" void kernel_launch(void* const* d_in, const int* in_sizes, int n_in,
                              void* d_out, int out_size, void* d_ws, size_t ws_size,
                              hipStream_t stream) {
  const float* query = (const float*)d_in[0];
  const float* key   = (const float*)d_in[1];
  const float* value = (const float*)d_in[2];
  const float* wq    = (const float*)d_in[3];
  const float* wk    = (const float*)d_in[4];
  const float* wv    = (const float*)d_in[5];
  const float* va    = (const float*)d_in[6];
  const float* wo    = (const float*)d_in[7];

  float* out  = (float*)d_out;                 // (B,T,DM)
  float* attn = out + (size_t)BT * DM;         // (B,H,T,S)

  const size_t SEG = (size_t)BT * DM;          // 524288 floats = 2MB
  float* EQ  = (float*)d_ws;                   // [bh][t][d]
  float* EKT = EQ + SEG;                       // [bh][dc16][s][j4]
  float* Vw  = EKT + SEG;                      // [bh][s/2][d][2]
  float* att = Vw + SEG;                       // attended [b][t][h*64+d]

  proj_kernel<<<dim3(256, 3), 256, 0, stream>>>(query, key, value, wq, wk, wv, EQ, EKT, Vw);
  attn_kernel<<<dim3(2048), 256, 0, stream>>>(EQ, EKT, Vw, va, attn, att);
  outproj_kernel<<<dim3(512), 256, 0, stream>>>(att, wo, out);
}